// Round 1
// baseline (313.238 us; speedup 1.0000x reference)
//
#include <hip/hip_runtime.h>
#include <hip/hip_bf16.h>

#define N_ATOMS 8192
#define N_PAIR  131072
#define F       128
#define N_HEAD  8
#define FH      16
#define N_DEG   3
#define M_TOT   15
#define K_RBF   32
#define H_FILT  64
#define FILT_OUT 768
#define NDH     24   // N_DEG * N_HEAD

typedef __attribute__((ext_vector_type(8))) unsigned short u16x8;

__device__ __forceinline__ float bf2f(unsigned short u) {
    return __uint_as_float(((unsigned)u) << 16);
}

// ---------------- K0: segment starts (idx_i is sorted) ----------------
__global__ void k_seg(const int* __restrict__ idx_i, int* __restrict__ row_start) {
    int p = blockIdx.x * 256 + threadIdx.x;
    if (p >= N_PAIR) return;
    int ii = idx_i[p];
    int prev = (p == 0) ? -1 : idx_i[p - 1];
    for (int a = prev + 1; a <= ii; ++a) row_start[a] = p;
    if (p == N_PAIR - 1) {
        for (int a = ii + 1; a <= N_ATOMS; ++a) row_start[a] = N_PAIR;
    }
}

// ---------------- K1a: Qa[n,dhc] = Q[n,d,h,c]*a[d,h,c]; Ka likewise ----------------
__global__ __launch_bounds__(256) void k_qa(
    const float* __restrict__ x, const float* __restrict__ WQ,
    const float* __restrict__ WK, const float* __restrict__ avec,
    float* __restrict__ Qa, float* __restrict__ Ka)
{
    __shared__ float wq_l[N_DEG * N_HEAD * FH * FH]; // 6144
    __shared__ float wk_l[N_DEG * N_HEAD * FH * FH]; // 6144
    __shared__ float a_l[N_DEG * N_HEAD * 32];       // 768
    __shared__ float x_l[8][F];                      // 1024
    int tid = threadIdx.x;
    for (int e = tid; e < 6144; e += 256) { wq_l[e] = WQ[e]; wk_l[e] = WK[e]; }
    for (int e = tid; e < 768; e += 256) a_l[e] = avec[e];
    int n0 = blockIdx.x * 8;
    for (int e = tid; e < 8 * F; e += 256)
        x_l[e >> 7][e & 127] = x[(size_t)(n0 + (e >> 7)) * F + (e & 127)];
    __syncthreads();
    for (int o = tid; o < 8 * 768; o += 256) {
        int at = o / 768; int r = o % 768;
        int side = r / 384; int dhc = r % 384;
        int dh = dhc >> 4; int c = dhc & 15;
        const float* Wl = (side == 0) ? wq_l : wk_l;
        int xb = (dh & 7) * 16; // h*16
        float s = 0.f;
        #pragma unroll
        for (int j = 0; j < 16; ++j) s += Wl[dhc * 16 + j] * x_l[at][xb + j];
        float av = a_l[dh * 32 + (side << 4) + c];
        float* Out = (side == 0) ? Qa : Ka;
        Out[(size_t)(n0 + at) * 384 + dhc] = s * av;
    }
}

// ---------------- K1b: Gq[n,dh,k] = sum_c W2[k,dhc]*Qa[n,dhc]; bq[n,dh] = sum_c b2*Qa ----------------
__global__ __launch_bounds__(256) void k_g(
    const float* __restrict__ Qa, const float* __restrict__ Ka,
    const float* __restrict__ W2, const float* __restrict__ b2,
    __hip_bfloat16* __restrict__ Gq, __hip_bfloat16* __restrict__ Gk,
    float* __restrict__ bq, float* __restrict__ bk)
{
    __shared__ float w2s[H_FILT][FH]; // 64x16
    __shared__ float qas[64][FH];     // 64 atoms x 16
    __shared__ float b2s[FH];
    int tid = threadIdx.x;
    int n0 = blockIdx.x * 64;
    int sdh = blockIdx.y;            // 0..47
    int side = sdh / NDH, dh = sdh % NDH;
    int d = dh >> 3, h = dh & 7;
    int colbase = d * 256 + h * 32 + side * 16;
    const float* Src = (side == 0) ? Qa : Ka;
    for (int e = tid; e < 64 * 16; e += 256) {
        int k = e >> 4, c = e & 15;
        w2s[k][c] = W2[k * FILT_OUT + colbase + c];
    }
    for (int e = tid; e < 64 * 16; e += 256) {
        int at = e >> 4, c = e & 15;
        qas[at][c] = Src[(size_t)(n0 + at) * 384 + dh * 16 + c];
    }
    if (tid < 16) b2s[tid] = b2[colbase + tid];
    __syncthreads();
    __hip_bfloat16* G = (side == 0) ? Gq : Gk;
    float* B = (side == 0) ? bq : bk;
    for (int o = tid; o < 64 * 64; o += 256) {
        int at = o >> 6, k = o & 63;
        float s = 0.f;
        #pragma unroll
        for (int c = 0; c < 16; ++c) s += qas[at][c] * w2s[k][c];
        G[(size_t)(n0 + at) * 1536 + dh * 64 + k] = __float2bfloat16(s);
        if (k == 0) {
            float sb = 0.f;
            #pragma unroll
            for (int c = 0; c < 16; ++c) sb += qas[at][c] * b2s[c];
            B[(n0 + at) * NDH + dh] = sb;
        }
    }
}

// ---------------- K2: per-pair alpha[p,dh] ----------------
__global__ __launch_bounds__(256) void k_alpha(
    const float* __restrict__ rbf, const float* __restrict__ phi,
    const float* __restrict__ mask,
    const int* __restrict__ idx_i, const int* __restrict__ idx_j,
    const float* __restrict__ W1, const float* __restrict__ b1v,
    const __hip_bfloat16* __restrict__ Gq, const __hip_bfloat16* __restrict__ Gk,
    const float* __restrict__ bq, const float* __restrict__ bk,
    float* __restrict__ alpha)
{
    __shared__ float w1s[K_RBF][H_FILT]; // 8 KB
    __shared__ float b1s[H_FILT];
    __shared__ float rbfs[8][K_RBF];
    __shared__ float h1s[8][H_FILT];
    int tid = threadIdx.x;
    for (int e = tid; e < K_RBF * H_FILT; e += 256) w1s[e >> 6][e & 63] = W1[e];
    if (tid < H_FILT) b1s[tid] = b1v[tid];
    int p0 = blockIdx.x * 8;
    rbfs[tid >> 5][tid & 31] = rbf[(size_t)p0 * K_RBF + tid];
    __syncthreads();
    int pp = tid >> 5;   // pair within block (0..7)
    int lane = tid & 31;
    int p = p0 + pp;
    // h1 = silu(rbf @ W1 + b1); each thread computes 2 of 64 outputs
    #pragma unroll
    for (int kk = 0; kk < 2; ++kk) {
        int k = lane + kk * 32;
        float s = b1s[k];
        #pragma unroll
        for (int c = 0; c < K_RBF; ++c) s += rbfs[pp][c] * w1s[c][k];
        h1s[pp][k] = s / (1.f + expf(-s));
    }
    __syncthreads();
    if (lane < NDH) {
        int dh = lane;
        int i = idx_i[p], j = idx_j[p];
        float acc = bq[i * NDH + dh] + bk[j * NDH + dh];
        const __hip_bfloat16* gq = Gq + (size_t)i * 1536 + dh * 64;
        const __hip_bfloat16* gk = Gk + (size_t)j * 1536 + dh * 64;
        #pragma unroll
        for (int v = 0; v < 8; ++v) {
            u16x8 qv = *reinterpret_cast<const u16x8*>(gq + v * 8);
            u16x8 kv = *reinterpret_cast<const u16x8*>(gk + v * 8);
            #pragma unroll
            for (int e = 0; e < 8; ++e) {
                acc += (bf2f(qv[e]) + bf2f(kv[e])) * h1s[pp][v * 8 + e];
            }
        }
        alpha[(size_t)p * NDH + dh] = acc * phi[p] * mask[p] * 0.25f;
    }
}

// ---------------- K3: per-atom segment aggregation ----------------
__global__ __launch_bounds__(128) void k_aggr(
    const float* __restrict__ x, const float* __restrict__ sph,
    const float* __restrict__ mask, const int* __restrict__ idx_j,
    const float* __restrict__ alpha, const int* __restrict__ row_start,
    float* __restrict__ out)
{
    int i = blockIdx.x;
    int tid = threadIdx.x; // f = tid, 128 threads
    int h = tid >> 4;
    float acc[M_TOT];
    #pragma unroll
    for (int m = 0; m < M_TOT; ++m) acc[m] = 0.f;
    int pstart = row_start[i], pend = row_start[i + 1];
    __shared__ float al[8][NDH];
    __shared__ float sl[8][M_TOT];
    __shared__ float xml[8];
    __shared__ int   jl[8];
    for (int pc = pstart; pc < pend; pc += 8) {
        int nb = min(8, pend - pc);
        __syncthreads();
        for (int e = tid; e < nb * NDH; e += 128)
            al[e / NDH][e % NDH] = alpha[(size_t)(pc + e / NDH) * NDH + e % NDH];
        for (int e = tid; e < nb * M_TOT; e += 128)
            sl[e / M_TOT][e % M_TOT] = sph[(size_t)(pc + e / M_TOT) * M_TOT + e % M_TOT];
        if (tid < nb) { xml[tid] = mask[pc + tid]; jl[tid] = idx_j[pc + tid]; }
        __syncthreads();
        for (int q = 0; q < nb; ++q) {
            int j = jl[q];
            float xv = x[(size_t)j * F + tid] * xml[q];
            float c0 = al[q][0 + h], c1 = al[q][8 + h], c2 = al[q][16 + h];
            #pragma unroll
            for (int m = 0; m < 3; ++m)  acc[m] += c0 * sl[q][m] * xv;
            #pragma unroll
            for (int m = 3; m < 8; ++m)  acc[m] += c1 * sl[q][m] * xv;
            #pragma unroll
            for (int m = 8; m < 15; ++m) acc[m] += c2 * sl[q][m] * xv;
        }
    }
    size_t ob = (size_t)i * (M_TOT * F) + tid;
    #pragma unroll
    for (int m = 0; m < M_TOT; ++m) out[ob + m * F] = acc[m];
}

extern "C" void kernel_launch(void* const* d_in, const int* in_sizes, int n_in,
                              void* d_out, int out_size, void* d_ws, size_t ws_size,
                              hipStream_t stream) {
    const float* x     = (const float*)d_in[0];
    const float* rbf   = (const float*)d_in[1];
    const float* sph   = (const float*)d_in[2];
    const float* phi   = (const float*)d_in[3];
    const int*   idx_i = (const int*)d_in[4];
    const int*   idx_j = (const int*)d_in[5];
    const float* mask  = (const float*)d_in[6];
    const float* WQ    = (const float*)d_in[7];
    const float* WK    = (const float*)d_in[8];
    const float* av    = (const float*)d_in[9];
    const float* W1    = (const float*)d_in[10];
    const float* b1    = (const float*)d_in[11];
    const float* W2    = (const float*)d_in[12];
    const float* b2    = (const float*)d_in[13];
    float* out = (float*)d_out;
    char* ws = (char*)d_ws;

    // ws layout (bytes). alpha aliases Qa (Qa dead after k_g).
    // Qa:    [0, 12582912)           8192*384*4
    // Ka:    [12582912, 25165824)
    // Gq:    [25165824, 50331648)    8192*1536*2 (bf16)
    // Gk:    [50331648, 75497472)
    // bq:    [75497472, 76283904)    8192*24*4
    // bk:    [76283904, 77070336)
    // alpha: [0, 12582912)           131072*24*4  (aliases Qa)
    // row_start: [77070336, 77103108)
    float* Qa = (float*)(ws + 0);
    float* Ka = (float*)(ws + 12582912);
    __hip_bfloat16* Gq = (__hip_bfloat16*)(ws + 25165824);
    __hip_bfloat16* Gk = (__hip_bfloat16*)(ws + 50331648);
    float* bq = (float*)(ws + 75497472);
    float* bk = (float*)(ws + 76283904);
    float* alphaBuf = (float*)(ws + 0);
    int* row_start = (int*)(ws + 77070336);

    k_seg<<<(N_PAIR + 255) / 256, 256, 0, stream>>>(idx_i, row_start);
    k_qa<<<N_ATOMS / 8, 256, 0, stream>>>(x, WQ, WK, av, Qa, Ka);
    dim3 gg(N_ATOMS / 64, 48);
    k_g<<<gg, 256, 0, stream>>>(Qa, Ka, W2, b2, Gq, Gk, bq, bk);
    k_alpha<<<N_PAIR / 8, 256, 0, stream>>>(rbf, phi, mask, idx_i, idx_j,
                                            W1, b1, Gq, Gk, bq, bk, alphaBuf);
    k_aggr<<<N_ATOMS, 128, 0, stream>>>(x, sph, mask, idx_j, alphaBuf, row_start, out);
}